// Round 5
// baseline (482.000 us; speedup 1.0000x reference)
//
#include <hip/hip_runtime.h>
#include <hip/hip_bf16.h>

typedef unsigned short u16;
typedef unsigned int u32;
typedef unsigned long long u64;
typedef __attribute__((ext_vector_type(8))) short s16x8;
typedef __attribute__((ext_vector_type(4))) short s16x4;
typedef __attribute__((ext_vector_type(4))) float f32x4;

__device__ inline u16 f2bf(float x) {
    u32 u = __float_as_uint(x);
    u32 r = (u + 0x7fffu + ((u >> 16) & 1u)) >> 16;
    return (u16)r;
}
__device__ inline float bf2f(u16 u) {
    return __uint_as_float(((u32)u) << 16);
}

// ---- features f32 -> bf16, with zero sentinel row at index N ----
__global__ void k_feat2bf(const float* __restrict__ f, u16* __restrict__ o,
                          int total, int nvalid) {
    int i = (blockIdx.x * 256 + threadIdx.x) * 8;
    if (i >= total) return;
    s16x8 v;
#pragma unroll
    for (int j = 0; j < 8; ++j) {
        float x = (i + j < nvalid) ? f[i + j] : 0.f;
        v[j] = (short)f2bf(x);
    }
    *(s16x8*)(o + i) = v;
}

// ---- weight swizzle (optionally row-scaled): W[9][cin][128] f32 -> MFMA-B
// fragment-packed bf16. W'[t][k][c] = W[t][k][c] * (sc ? sc[k] : 1)
__global__ void k_swz(const float* __restrict__ W, const float* __restrict__ sc,
                      u16* __restrict__ o, int cin) {
    int i = blockIdx.x * 256 + threadIdx.x;
    int total = 9 * cin * 128;
    if (i >= total) return;
    int j = i & 7;
    int l = (i >> 3) & 63;
    int fr = i >> 9;
    int ct = fr & 7;
    int rest = fr >> 3;
    int kcn = cin >> 5;
    int kc = rest % kcn;
    int t = rest / kcn;
    int kk = kc * 32 + (l >> 4) * 8 + j;
    int c = ct * 16 + (l & 15);
    float v = W[(t * cin + kk) * 128 + c];
    if (sc) v *= sc[kk];
    o[i] = f2bf(v);
}

// ---- u_t[c] = sum_k sh[k] * W[t][k][c]  (bias term per valid tap) ----
__global__ void k_ubias(const float* __restrict__ W, const float* __restrict__ sh,
                        float* __restrict__ u, int cin) {
    int c = threadIdx.x;    // 0..127
    int t = blockIdx.x;     // 0..8
    float s = 0.f;
    for (int k = 0; k < cin; ++k) s += sh[k] * W[(t * cin + k) * 128 + c];
    u[t * 128 + c] = s;
}

// ---- gather-conv: block = 1024 thr (16 waves x 32 voxels) x 64 output cols.
// blockIdx.y = column half, blockIdx.z selects conv {A,B}. All taps' weights
// staged in LDS once (no loop barriers). Pair-level tap skipping via ballot;
// B-frags shared across both row-groups; nbr 2-ahead / A 1-ahead pipeline.
// AFF: adds per-valid-tap bias u_t (folded BN shift).
template <int CIN, bool AFF>
__global__ __launch_bounds__(1024) void k_conv(
    const u16* __restrict__ srcA, const u16* __restrict__ srcB,
    const int* __restrict__ nbrA, const int* __restrict__ nbrB,
    const u16* __restrict__ wA, const u16* __restrict__ wB,
    const float* __restrict__ uA, const float* __restrict__ uB,
    u16* __restrict__ zoutA, u16* __restrict__ zoutB,
    float* __restrict__ statsA, float* __restrict__ statsB,
    int N) {
    constexpr int KC = CIN / 32;
    constexpr int FR = 9 * KC * 4;
    constexpr int UB = AFF ? 9 * 128 : 4;
    __shared__ u16 wl[FR * 512];
    __shared__ float sstat[128];
    __shared__ float ubuf[UB];

    const int tid = threadIdx.x;
    const int half = blockIdx.y;
    const int cz = blockIdx.z;
    const u16* __restrict__ src = cz ? srcB : srcA;
    const int* __restrict__ nbr = cz ? nbrB : nbrA;
    const u16* __restrict__ w = cz ? wB : wA;
    u16* __restrict__ zout = cz ? zoutB : zoutA;
    float* __restrict__ stats = cz ? statsB : statsA;

    // stage this half's weights for all taps; stage u; zero stats
    for (int i = tid; i < FR * 64; i += 1024) {
        int p = i & 63;
        int f = i >> 6;
        int ctp = f & 3;
        int tk = f >> 2;
        s16x8 v = *(const s16x8*)(w + ((size_t)(tk * 8 + half * 4 + ctp)) * 512 + p * 8);
        *(s16x8*)&wl[(size_t)f * 512 + p * 8] = v;
    }
    if (AFF) {
        const float* __restrict__ u = cz ? uB : uA;
        for (int i = tid; i < 9 * 128; i += 1024) ubuf[i] = u[i];
    }
    if (tid < 128) sstat[tid] = 0.f;
    __syncthreads();

    const int lane = tid & 63;
    const int wv = tid >> 6;
    const int base = blockIdx.x * 512 + wv * 32;
    const int am = lane & 15;
    const int grp = lane >> 4;
    const int vi0 = base + am;
    const int vi1 = base + 16 + am;

    int r0[9], r1[9];
    u64 m0[9], m1[9];
    bool e[9];
    s16x8 a0[2][KC], a1[2][KC];

    // prologue: nbr taps 0,1; mask 0; A tap 0
    r0[0] = (vi0 < N) ? nbr[vi0] : N;
    r1[0] = (vi1 < N) ? nbr[vi1] : N;
    r0[1] = (vi0 < N) ? nbr[N + vi0] : N;
    r1[1] = (vi1 < N) ? nbr[N + vi1] : N;
    m0[0] = __ballot(r0[0] != N);
    m1[0] = __ballot(r1[0] != N);
    e[0] = (m0[0] | m1[0]) != 0ULL;
    {
        const u16* sp0 = src + (size_t)r0[0] * CIN + grp * 8;
        const u16* sp1 = src + (size_t)r1[0] * CIN + grp * 8;
#pragma unroll
        for (int kc = 0; kc < KC; ++kc) {
            a0[0][kc] = *(const s16x8*)(sp0 + kc * 32);
            a1[0][kc] = *(const s16x8*)(sp1 + kc * 32);
        }
    }

    f32x4 acc0[4], acc1[4];
#pragma unroll
    for (int c = 0; c < 4; ++c) {
        acc0[c] = (f32x4){0.f, 0.f, 0.f, 0.f};
        acc1[c] = (f32x4){0.f, 0.f, 0.f, 0.f};
    }

#pragma unroll
    for (int t = 0; t < 9; ++t) {
        const int cur = t & 1, nxt = cur ^ 1;
        if (t + 2 < 9) {
            r0[t + 2] = (vi0 < N) ? nbr[(t + 2) * N + vi0] : N;
            r1[t + 2] = (vi1 < N) ? nbr[(t + 2) * N + vi1] : N;
        }
        if (t + 1 < 9) {
            m0[t + 1] = __ballot(r0[t + 1] != N);
            m1[t + 1] = __ballot(r1[t + 1] != N);
            e[t + 1] = (m0[t + 1] | m1[t + 1]) != 0ULL;
            const u16* sp0 = src + (size_t)r0[t + 1] * CIN + grp * 8;
            const u16* sp1 = src + (size_t)r1[t + 1] * CIN + grp * 8;
#pragma unroll
            for (int kc = 0; kc < KC; ++kc) {
                a0[nxt][kc] = *(const s16x8*)(sp0 + kc * 32);
                a1[nxt][kc] = *(const s16x8*)(sp1 + kc * 32);
            }
        }
        if (e[t]) {
            const u16* lb = wl + (size_t)t * (KC * 4) * 512 + lane * 8;
#pragma unroll
            for (int kc = 0; kc < KC; ++kc) {
#pragma unroll
                for (int c = 0; c < 4; ++c) {
                    s16x8 b = *(const s16x8*)(lb + (kc * 4 + c) * 512);
                    acc0[c] = __builtin_amdgcn_mfma_f32_16x16x32_bf16(a0[cur][kc], b, acc0[c], 0, 0, 0);
                    acc1[c] = __builtin_amdgcn_mfma_f32_16x16x32_bf16(a1[cur][kc], b, acc1[c], 0, 0, 0);
                }
            }
        }
    }

    // epilogue: (+bias term), lrelu, bf16 store, block-local stats
#pragma unroll
    for (int c = 0; c < 4; ++c) {
        float s = 0.f, q = 0.f;
        const int col = half * 64 + c * 16 + am;
        float uv[9];
        if (AFF) {
#pragma unroll
            for (int t = 0; t < 9; ++t) uv[t] = ubuf[t * 128 + col];
        }
#pragma unroll
        for (int j = 0; j < 4; ++j) {
            const int r = grp * 4 + j;
            float ub0 = 0.f, ub1 = 0.f;
            if (AFF) {
#pragma unroll
                for (int t = 0; t < 9; ++t) {
                    if ((m0[t] >> r) & 1) ub0 += uv[t];
                    if ((m1[t] >> r) & 1) ub1 += uv[t];
                }
            }
            {
                float x = acc0[c][j] + ub0;
                float z = (x > 0.f) ? x : 0.01f * x;
                int row = base + r;
                if (row < N) zout[(size_t)row * 128 + col] = f2bf(z);
                s += z;
                q += z * z;
            }
            {
                float x = acc1[c][j] + ub1;
                float z = (x > 0.f) ? x : 0.01f * x;
                int row = base + 16 + r;
                if (row < N) zout[(size_t)row * 128 + col] = f2bf(z);
                s += z;
                q += z * z;
            }
        }
        s += __shfl_xor(s, 16);
        q += __shfl_xor(q, 16);
        s += __shfl_xor(s, 32);
        q += __shfl_xor(q, 32);
        if (lane < 16) {
            atomicAdd(&sstat[c * 16 + am], s);
            atomicAdd(&sstat[64 + c * 16 + am], q);
        }
    }
    __syncthreads();
    if (tid < 64) {
        int cg = half * 64 + tid;
        atomicAdd(stats + cg, sstat[tid]);
        atomicAdd(stats + 128 + cg, sstat[64 + tid]);
    }
}

// ---- finalize two BN stat sets -> per-channel scale/shift ----
__global__ void k_fin(const float* __restrict__ stats,
                      const float* __restrict__ g0, const float* __restrict__ b0,
                      const float* __restrict__ g1, const float* __restrict__ b1,
                      float* __restrict__ ss, int N) {
    int tid = threadIdx.x;
    int set = tid >> 7, c = tid & 127;
    const float* st = stats + set * 256;
    float invN = 1.f / (float)N;
    float m = st[c] * invN;
    float var = st[128 + c] * invN - m * m;
    const float* g = set ? g1 : g0;
    const float* b = set ? b1 : b0;
    float sc = g[c] * rsqrtf(var + 1e-5f);
    float sh = b[c] - m * sc;
    float* o = ss + set * 256;
    o[c] = sc;
    o[128 + c] = sh;
}

// ---- out = bn(z3) + bn(z4), f32 ----
__global__ void k_final(const u16* __restrict__ z3, const u16* __restrict__ z4,
                        const float* __restrict__ ssA, const float* __restrict__ ssB,
                        float* __restrict__ out, int N) {
    int v = blockIdx.x * 256 + threadIdx.x;
    int total = N * 32;
    if (v >= total) return;
    int row = v >> 5;
    int cb = (v & 31) * 4;
    s16x4 a = *(const s16x4*)(z3 + (size_t)row * 128 + cb);
    s16x4 b = *(const s16x4*)(z4 + (size_t)row * 128 + cb);
    f32x4 o;
#pragma unroll
    for (int j = 0; j < 4; ++j) {
        int c = cb + j;
        o[j] = bf2f((u16)a[j]) * ssA[c] + ssA[128 + c] +
               bf2f((u16)b[j]) * ssB[c] + ssB[128 + c];
    }
    *(f32x4*)(out + (size_t)row * 128 + cb) = o;
}

extern "C" void kernel_launch(void* const* d_in, const int* in_sizes, int n_in,
                              void* d_out, int out_size, void* d_ws, size_t ws_size,
                              hipStream_t stream) {
    const float* feat = (const float*)d_in[0];
    const int* nbr31 = (const int*)d_in[1];
    const int* nbr13 = (const int*)d_in[2];
    const float* W1 = (const float*)d_in[3];
    const float* W12 = (const float*)d_in[4];
    const float* W2 = (const float*)d_in[5];
    const float* W3 = (const float*)d_in[6];
    const float* g0 = (const float*)d_in[7];
    const float* b0 = (const float*)d_in[8];
    const float* g02 = (const float*)d_in[9];
    const float* b02 = (const float*)d_in[10];
    const float* g1 = (const float*)d_in[11];
    const float* b1 = (const float*)d_in[12];
    const float* g2 = (const float*)d_in[13];
    const float* b2 = (const float*)d_in[14];
    float* out = (float*)d_out;
    const int N = in_sizes[0] / 64;  // 200000

    char* p = (char*)d_ws;
    auto alloc = [&](size_t bytes) {
        char* r = p;
        p += (bytes + 255) & ~(size_t)255;
        return r;
    };
    float* stats = (float*)alloc(4 * 256 * sizeof(float));
    float* ss = (float*)alloc(4 * 256 * sizeof(float));
    float* u12 = (float*)alloc(9 * 128 * sizeof(float));
    float* u3 = (float*)alloc(9 * 128 * sizeof(float));
    u16* featbf = (u16*)alloc((size_t)(N + 1) * 64 * 2);
    u16* w1 = (u16*)alloc((size_t)9 * 64 * 128 * 2);
    u16* w2 = (u16*)alloc((size_t)9 * 64 * 128 * 2);
    u16* w12 = (u16*)alloc((size_t)9 * 128 * 128 * 2);
    u16* w3 = (u16*)alloc((size_t)9 * 128 * 128 * 2);
    u16* zA = (u16*)alloc((size_t)(N + 1) * 128 * 2);   // stage-1 out (sentinel row)
    u16* zB = (u16*)alloc((size_t)(N + 1) * 128 * 2);
    u16* z2A = (u16*)alloc((size_t)N * 128 * 2);        // stage-2 out
    u16* z2B = (u16*)alloc((size_t)N * 128 * 2);

    hipMemsetAsync(stats, 0, 4 * 256 * sizeof(float), stream);
    hipMemsetAsync(zA + (size_t)N * 128, 0, 256, stream);  // sentinel rows
    hipMemsetAsync(zB + (size_t)N * 128, 0, 256, stream);

    int totF = (N + 1) * 64;
    k_feat2bf<<<(totF / 8 + 255) / 256, 256, 0, stream>>>(feat, featbf, totF, N * 64);
    k_swz<<<(9 * 64 * 128 + 255) / 256, 256, 0, stream>>>(W1, nullptr, w1, 64);
    k_swz<<<(9 * 64 * 128 + 255) / 256, 256, 0, stream>>>(W2, nullptr, w2, 64);

    dim3 cgrid((N + 511) / 512, 2, 2);
    // stage 1: z=0: conv(nbr31, W1) -> zA/stats0 ; z=1: conv(nbr13, W2) -> zB/stats1
    k_conv<64, false><<<cgrid, 1024, 0, stream>>>(
        featbf, featbf, nbr31, nbr13, w1, w2, nullptr, nullptr,
        zA, zB, stats + 0, stats + 256, N);
    k_fin<<<1, 256, 0, stream>>>(stats, g0, b0, g1, b1, ss, N);

    // stage-2 weights: scaled by BN scale; bias term u_t = sh @ W_t
    k_swz<<<(9 * 128 * 128 + 255) / 256, 256, 0, stream>>>(W12, ss + 0, w12, 128);
    k_swz<<<(9 * 128 * 128 + 255) / 256, 256, 0, stream>>>(W3, ss + 256, w3, 128);
    k_ubias<<<9, 128, 0, stream>>>(W12, ss + 128, u12, 128);
    k_ubias<<<9, 128, 0, stream>>>(W3, ss + 256 + 128, u3, 128);

    // stage 2: z=0: conv(zA, nbr13, W12') ; z=1: conv(zB, nbr31, W3')
    k_conv<128, true><<<cgrid, 1024, 0, stream>>>(
        zA, zB, nbr13, nbr31, w12, w3, u12, u3,
        z2A, z2B, stats + 512, stats + 768, N);
    k_fin<<<1, 256, 0, stream>>>(stats + 512, g02, b02, g2, b2, ss + 512, N);
    k_final<<<(N * 32 + 255) / 256, 256, 0, stream>>>(z2A, z2B, ss + 512, ss + 768, out, N);
}

// Round 6
// 454.464 us; speedup vs baseline: 1.0606x; 1.0606x over previous
//
#include <hip/hip_runtime.h>
#include <hip/hip_bf16.h>

typedef unsigned short u16;
typedef unsigned int u32;
typedef __attribute__((ext_vector_type(8))) short s16x8;
typedef __attribute__((ext_vector_type(4))) short s16x4;
typedef __attribute__((ext_vector_type(4))) float f32x4;

__device__ inline u16 f2bf(float x) {
    u32 u = __float_as_uint(x);
    u32 r = (u + 0x7fffu + ((u >> 16) & 1u)) >> 16;
    return (u16)r;
}
__device__ inline float bf2f(u16 u) {
    return __uint_as_float(((u32)u) << 16);
}

// ---- features f32 -> bf16, with zero sentinel row at index N ----
__global__ void k_feat2bf(const float* __restrict__ f, u16* __restrict__ o,
                          int total, int nvalid) {
    int i = (blockIdx.x * 256 + threadIdx.x) * 8;
    if (i >= total) return;
    s16x8 v;
#pragma unroll
    for (int j = 0; j < 8; ++j) {
        float x = (i + j < nvalid) ? f[i + j] : 0.f;
        v[j] = (short)f2bf(x);
    }
    *(s16x8*)(o + i) = v;
}

// ---- weight swizzle: W[9][cin][128] f32 -> MFMA-B fragment-packed bf16 ----
// frag index fr = (tap*KC + kc)*8 + ct ; within frag: lane l holds 8 contiguous
// bf16 at fr*512 + l*8, element j = B[kc*32 + (l>>4)*8 + j][ct*16 + (l&15)]
__global__ void k_swz(const float* __restrict__ W, u16* __restrict__ o, int cin) {
    int i = blockIdx.x * 256 + threadIdx.x;
    int total = 9 * cin * 128;
    if (i >= total) return;
    int j = i & 7;
    int l = (i >> 3) & 63;
    int fr = i >> 9;
    int ct = fr & 7;
    int rest = fr >> 3;
    int kcn = cin >> 5;
    int kc = rest % kcn;
    int t = rest / kcn;
    int kk = kc * 32 + (l >> 4) * 8 + j;
    int c = ct * 16 + (l & 15);
    o[i] = f2bf(W[(t * cin + kk) * 128 + c]);
}

// ---- gather-conv: block = 1024 thr (16 waves x 32 voxels) x 32 output cols.
// blockIdx.y = column quarter (0..3), blockIdx.z selects conv {A,B}.
// All taps' weights staged in LDS once (no loop barriers). Pair-level tap
// skipping; each B ds_read feeds 2 MFMAs (both row-groups). 2 blocks/CU.
template <int CIN>
__global__ __launch_bounds__(1024, 8) void k_conv(
    const u16* __restrict__ srcA, const u16* __restrict__ srcB,
    const int* __restrict__ nbrA, const int* __restrict__ nbrB,
    const u16* __restrict__ wA, const u16* __restrict__ wB,
    u16* __restrict__ zoutA, u16* __restrict__ zoutB,
    float* __restrict__ statsA, float* __restrict__ statsB,
    int N) {
    constexpr int KC = CIN / 32;
    constexpr int FR = 9 * KC * 2;    // frags staged (2 col-tiles of 16)
    __shared__ u16 wl[FR * 512];
    __shared__ float sstat[64];

    const int tid = threadIdx.x;
    const int half = blockIdx.y;     // column quarter
    const int cz = blockIdx.z;
    const u16* __restrict__ src = cz ? srcB : srcA;
    const int* __restrict__ nbr = cz ? nbrB : nbrA;
    const u16* __restrict__ w = cz ? wB : wA;
    u16* __restrict__ zout = cz ? zoutB : zoutA;
    float* __restrict__ stats = cz ? statsB : statsA;

    // stage this quarter's weights for all taps; zero stats
    for (int i = tid; i < FR * 64; i += 1024) {
        int p = i & 63;
        int f = i >> 6;          // (t*KC+kc)*2 + ctp
        int ctp = f & 1;
        int tk = f >> 1;
        s16x8 v = *(const s16x8*)(w + ((size_t)(tk * 8 + half * 2 + ctp)) * 512 + p * 8);
        *(s16x8*)&wl[(size_t)f * 512 + p * 8] = v;
    }
    if (tid < 64) sstat[tid] = 0.f;
    __syncthreads();

    const int lane = tid & 63;
    const int wv = tid >> 6;
    const int base = blockIdx.x * 512 + wv * 32;
    const int am = lane & 15;
    const int grp = lane >> 4;
    const int vi0 = base + am;
    const int vi1 = base + 16 + am;

    int r0[9], r1[9];
#pragma unroll
    for (int t = 0; t < 9; ++t) {
        r0[t] = (vi0 < N) ? nbr[t * N + vi0] : N;
        r1[t] = (vi1 < N) ? nbr[t * N + vi1] : N;
    }

    f32x4 acc0[2], acc1[2];
#pragma unroll
    for (int c = 0; c < 2; ++c) {
        acc0[c] = (f32x4){0.f, 0.f, 0.f, 0.f};
        acc1[c] = (f32x4){0.f, 0.f, 0.f, 0.f};
    }

#pragma unroll
    for (int t = 0; t < 9; ++t) {
        if (__any((r0[t] != N) || (r1[t] != N))) {
            const u16* sp0 = src + (size_t)r0[t] * CIN + grp * 8;
            const u16* sp1 = src + (size_t)r1[t] * CIN + grp * 8;
            const u16* lb = wl + (size_t)t * (KC * 2) * 512 + lane * 8;
#pragma unroll
            for (int kc = 0; kc < KC; ++kc) {
                s16x8 a0 = *(const s16x8*)(sp0 + kc * 32);
                s16x8 a1 = *(const s16x8*)(sp1 + kc * 32);
#pragma unroll
                for (int c = 0; c < 2; ++c) {
                    s16x8 b = *(const s16x8*)(lb + (kc * 2 + c) * 512);
                    acc0[c] = __builtin_amdgcn_mfma_f32_16x16x32_bf16(a0, b, acc0[c], 0, 0, 0);
                    acc1[c] = __builtin_amdgcn_mfma_f32_16x16x32_bf16(a1, b, acc1[c], 0, 0, 0);
                }
            }
        }
    }

    // epilogue: lrelu, bf16 store, block-local stats
#pragma unroll
    for (int c = 0; c < 2; ++c) {
        float s = 0.f, q = 0.f;
        const int col = half * 32 + c * 16 + am;
#pragma unroll
        for (int j = 0; j < 4; ++j) {
            {
                float x = acc0[c][j];
                float z = (x > 0.f) ? x : 0.01f * x;
                int row = base + grp * 4 + j;
                if (row < N) zout[(size_t)row * 128 + col] = f2bf(z);
                s += z;
                q += z * z;
            }
            {
                float x = acc1[c][j];
                float z = (x > 0.f) ? x : 0.01f * x;
                int row = base + 16 + grp * 4 + j;
                if (row < N) zout[(size_t)row * 128 + col] = f2bf(z);
                s += z;
                q += z * z;
            }
        }
        s += __shfl_xor(s, 16);
        q += __shfl_xor(q, 16);
        s += __shfl_xor(s, 32);
        q += __shfl_xor(q, 32);
        if (lane < 16) {
            atomicAdd(&sstat[c * 16 + am], s);
            atomicAdd(&sstat[32 + c * 16 + am], q);
        }
    }
    __syncthreads();
    if (tid < 32) {
        int cg = half * 32 + tid;
        atomicAdd(stats + cg, sstat[tid]);
        atomicAdd(stats + 128 + cg, sstat[32 + tid]);
    }
}

// ---- finalize two BN stat sets -> per-channel scale/shift ----
__global__ void k_fin(const float* __restrict__ stats,
                      const float* __restrict__ g0, const float* __restrict__ b0,
                      const float* __restrict__ g1, const float* __restrict__ b1,
                      float* __restrict__ ss, int N) {
    int tid = threadIdx.x;
    int set = tid >> 7, c = tid & 127;
    const float* st = stats + set * 256;
    float invN = 1.f / (float)N;
    float m = st[c] * invN;
    float var = st[128 + c] * invN - m * m;
    const float* g = set ? g1 : g0;
    const float* b = set ? b1 : b0;
    float sc = g[c] * rsqrtf(var + 1e-5f);
    float sh = b[c] - m * sc;
    float* o = ss + set * 256;
    o[c] = sc;
    o[128 + c] = sh;
}

// ---- y = z*scale + shift (bf16 out, with zero sentinel row N) ----
__global__ void k_aff(const u16* __restrict__ z, const float* __restrict__ ss,
                      u16* __restrict__ y, int N) {
    int v = blockIdx.x * 256 + threadIdx.x;
    int total = (N + 1) * 16;
    if (v >= total) return;
    int row = v >> 4;
    int cb = (v & 15) * 8;
    s16x8 o;
    if (row < N) {
        s16x8 zi = *(const s16x8*)(z + (size_t)row * 128 + cb);
#pragma unroll
        for (int j = 0; j < 8; ++j) {
            float x = bf2f((u16)zi[j]);
            float r = x * ss[cb + j] + ss[128 + cb + j];
            o[j] = (short)f2bf(r);
        }
    } else {
        o = (s16x8){0, 0, 0, 0, 0, 0, 0, 0};
    }
    *(s16x8*)(y + (size_t)row * 128 + cb) = o;
}

// ---- out = bn(z3) + bn(z4), f32 ----
__global__ void k_final(const u16* __restrict__ z3, const u16* __restrict__ z4,
                        const float* __restrict__ ssA, const float* __restrict__ ssB,
                        float* __restrict__ out, int N) {
    int v = blockIdx.x * 256 + threadIdx.x;
    int total = N * 32;
    if (v >= total) return;
    int row = v >> 5;
    int cb = (v & 31) * 4;
    s16x4 a = *(const s16x4*)(z3 + (size_t)row * 128 + cb);
    s16x4 b = *(const s16x4*)(z4 + (size_t)row * 128 + cb);
    f32x4 o;
#pragma unroll
    for (int j = 0; j < 4; ++j) {
        int c = cb + j;
        o[j] = bf2f((u16)a[j]) * ssA[c] + ssA[128 + c] +
               bf2f((u16)b[j]) * ssB[c] + ssB[128 + c];
    }
    *(f32x4*)(out + (size_t)row * 128 + cb) = o;
}

extern "C" void kernel_launch(void* const* d_in, const int* in_sizes, int n_in,
                              void* d_out, int out_size, void* d_ws, size_t ws_size,
                              hipStream_t stream) {
    const float* feat = (const float*)d_in[0];
    const int* nbr31 = (const int*)d_in[1];
    const int* nbr13 = (const int*)d_in[2];
    const float* W1 = (const float*)d_in[3];
    const float* W12 = (const float*)d_in[4];
    const float* W2 = (const float*)d_in[5];
    const float* W3 = (const float*)d_in[6];
    const float* g0 = (const float*)d_in[7];
    const float* b0 = (const float*)d_in[8];
    const float* g02 = (const float*)d_in[9];
    const float* b02 = (const float*)d_in[10];
    const float* g1 = (const float*)d_in[11];
    const float* b1 = (const float*)d_in[12];
    const float* g2 = (const float*)d_in[13];
    const float* b2 = (const float*)d_in[14];
    float* out = (float*)d_out;
    const int N = in_sizes[0] / 64;  // 200000

    char* p = (char*)d_ws;
    auto alloc = [&](size_t bytes) {
        char* r = p;
        p += (bytes + 255) & ~(size_t)255;
        return r;
    };
    float* stats = (float*)alloc(4 * 256 * sizeof(float));
    float* ss = (float*)alloc(4 * 256 * sizeof(float));
    u16* featbf = (u16*)alloc((size_t)(N + 1) * 64 * 2);
    u16* w1 = (u16*)alloc((size_t)9 * 64 * 128 * 2);
    u16* w2 = (u16*)alloc((size_t)9 * 64 * 128 * 2);
    u16* w12 = (u16*)alloc((size_t)9 * 128 * 128 * 2);
    u16* w3 = (u16*)alloc((size_t)9 * 128 * 128 * 2);
    u16* zA = (u16*)alloc((size_t)N * 128 * 2);
    u16* zB = (u16*)alloc((size_t)N * 128 * 2);
    u16* y1 = (u16*)alloc((size_t)(N + 1) * 128 * 2);
    u16* y2 = (u16*)alloc((size_t)(N + 1) * 128 * 2);

    hipMemsetAsync(stats, 0, 4 * 256 * sizeof(float), stream);

    int totF = (N + 1) * 64;
    k_feat2bf<<<(totF / 8 + 255) / 256, 256, 0, stream>>>(feat, featbf, totF, N * 64);
    k_swz<<<(9 * 64 * 128 + 255) / 256, 256, 0, stream>>>(W1, w1, 64);
    k_swz<<<(9 * 64 * 128 + 255) / 256, 256, 0, stream>>>(W2, w2, 64);
    k_swz<<<(9 * 128 * 128 + 255) / 256, 256, 0, stream>>>(W12, w12, 128);
    k_swz<<<(9 * 128 * 128 + 255) / 256, 256, 0, stream>>>(W3, w3, 128);

    dim3 cgrid((N + 511) / 512, 4, 2);
    // stage 1: z=0: conv(nbr31, W1) -> zA/stats0 ; z=1: conv(nbr13, W2) -> zB/stats1
    k_conv<64><<<cgrid, 1024, 0, stream>>>(
        featbf, featbf, nbr31, nbr13, w1, w2, zA, zB, stats + 0, stats + 256, N);
    k_fin<<<1, 256, 0, stream>>>(stats, g0, b0, g1, b1, ss, N);
    int ablk = ((N + 1) * 16 + 255) / 256;
    k_aff<<<ablk, 256, 0, stream>>>(zA, ss + 0, y1, N);
    k_aff<<<ablk, 256, 0, stream>>>(zB, ss + 256, y2, N);
    // stage 2: z=0: conv(y1, nbr13, W12) -> zA ; z=1: conv(y2, nbr31, W3) -> zB
    k_conv<128><<<cgrid, 1024, 0, stream>>>(
        y1, y2, nbr13, nbr31, w12, w3, zA, zB, stats + 512, stats + 768, N);
    k_fin<<<1, 256, 0, stream>>>(stats + 512, g02, b02, g2, b2, ss + 512, N);
    k_final<<<(N * 32 + 255) / 256, 256, 0, stream>>>(zA, zB, ss + 512, ss + 768, out, N);
}

// Round 7
// 453.662 us; speedup vs baseline: 1.0625x; 1.0018x over previous
//
#include <hip/hip_runtime.h>
#include <hip/hip_bf16.h>

typedef unsigned short u16;
typedef unsigned int u32;
typedef __attribute__((ext_vector_type(8))) short s16x8;
typedef __attribute__((ext_vector_type(4))) short s16x4;
typedef __attribute__((ext_vector_type(4))) float f32x4;

__device__ inline u16 f2bf(float x) {
    u32 u = __float_as_uint(x);
    u32 r = (u + 0x7fffu + ((u >> 16) & 1u)) >> 16;
    return (u16)r;
}
__device__ inline float bf2f(u16 u) {
    return __uint_as_float(((u32)u) << 16);
}

// ---- features f32 -> bf16, with zero sentinel row at index N ----
__global__ void k_feat2bf(const float* __restrict__ f, u16* __restrict__ o,
                          int total, int nvalid) {
    int i = (blockIdx.x * 256 + threadIdx.x) * 8;
    if (i >= total) return;
    s16x8 v;
#pragma unroll
    for (int j = 0; j < 8; ++j) {
        float x = (i + j < nvalid) ? f[i + j] : 0.f;
        v[j] = (short)f2bf(x);
    }
    *(s16x8*)(o + i) = v;
}

// ---- weight swizzle: W[9][cin][128] f32 -> MFMA-B fragment-packed bf16 ----
__global__ void k_swz(const float* __restrict__ W, u16* __restrict__ o, int cin) {
    int i = blockIdx.x * 256 + threadIdx.x;
    int total = 9 * cin * 128;
    if (i >= total) return;
    int j = i & 7;
    int l = (i >> 3) & 63;
    int fr = i >> 9;
    int ct = fr & 7;
    int rest = fr >> 3;
    int kcn = cin >> 5;
    int kc = rest % kcn;
    int t = rest / kcn;
    int kk = kc * 32 + (l >> 4) * 8 + j;
    int c = ct * 16 + (l & 15);
    o[i] = f2bf(W[(t * cin + kk) * 128 + c]);
}

// ---- gather-conv: 1024 thr (16 waves x 32 voxels) x 32 output cols.
// Flat 1-D grid with XCD-grouping remap: the 4 column-quarter blocks of one
// (voxel-range, conv) group get block ids == same (mod 8) and adjacent slots,
// so they co-reside on one XCD and share gathered A-rows in its L2.
// Pair-level tap skipping; each B ds_read feeds 2 MFMAs. 2 blocks/CU.
template <int CIN>
__global__ __launch_bounds__(1024, 8) void k_conv(
    const u16* __restrict__ srcA, const u16* __restrict__ srcB,
    const int* __restrict__ nbrA, const int* __restrict__ nbrB,
    const u16* __restrict__ wA, const u16* __restrict__ wB,
    u16* __restrict__ zoutA, u16* __restrict__ zoutB,
    float* __restrict__ statsA, float* __restrict__ statsB,
    int N) {
    constexpr int KC = CIN / 32;
    constexpr int FR = 9 * KC * 2;    // frags staged (2 col-tiles of 16)
    __shared__ u16 wl[FR * 512];
    __shared__ float sstat[64];

    // ---- block-id remap: i = c + 8*(4q + h); group p = 8q + c; quarter h ----
    const int nvr = (N + 511) >> 9;
    const int npairs = 2 * nvr;
    const int i = blockIdx.x;
    const int c8 = i & 7;
    const int m = i >> 3;
    const int h = m & 3;
    const int q = m >> 2;
    const int p = 8 * q + c8;
    if (p >= npairs) return;
    const int vr = p % nvr;
    const int cz = p / nvr;
    const int half = h;

    const u16* __restrict__ src = cz ? srcB : srcA;
    const int* __restrict__ nbr = cz ? nbrB : nbrA;
    const u16* __restrict__ w = cz ? wB : wA;
    u16* __restrict__ zout = cz ? zoutB : zoutA;
    float* __restrict__ stats = cz ? statsB : statsA;

    const int tid = threadIdx.x;

    // stage this quarter's weights for all taps; zero stats
    for (int ii = tid; ii < FR * 64; ii += 1024) {
        int pp = ii & 63;
        int f = ii >> 6;          // (t*KC+kc)*2 + ctp
        int ctp = f & 1;
        int tk = f >> 1;
        s16x8 v = *(const s16x8*)(w + ((size_t)(tk * 8 + half * 2 + ctp)) * 512 + pp * 8);
        *(s16x8*)&wl[(size_t)f * 512 + pp * 8] = v;
    }
    if (tid < 64) sstat[tid] = 0.f;
    __syncthreads();

    const int lane = tid & 63;
    const int wv = tid >> 6;
    const int base = vr * 512 + wv * 32;
    const int am = lane & 15;
    const int grp = lane >> 4;
    const int vi0 = base + am;
    const int vi1 = base + 16 + am;

    int r0[9], r1[9];
#pragma unroll
    for (int t = 0; t < 9; ++t) {
        r0[t] = (vi0 < N) ? nbr[t * N + vi0] : N;
        r1[t] = (vi1 < N) ? nbr[t * N + vi1] : N;
    }

    f32x4 acc0[2], acc1[2];
#pragma unroll
    for (int c = 0; c < 2; ++c) {
        acc0[c] = (f32x4){0.f, 0.f, 0.f, 0.f};
        acc1[c] = (f32x4){0.f, 0.f, 0.f, 0.f};
    }

#pragma unroll
    for (int t = 0; t < 9; ++t) {
        if (__any((r0[t] != N) || (r1[t] != N))) {
            const u16* sp0 = src + (size_t)r0[t] * CIN + grp * 8;
            const u16* sp1 = src + (size_t)r1[t] * CIN + grp * 8;
            const u16* lb = wl + (size_t)t * (KC * 2) * 512 + lane * 8;
#pragma unroll
            for (int kc = 0; kc < KC; ++kc) {
                s16x8 a0 = *(const s16x8*)(sp0 + kc * 32);
                s16x8 a1 = *(const s16x8*)(sp1 + kc * 32);
#pragma unroll
                for (int c = 0; c < 2; ++c) {
                    s16x8 b = *(const s16x8*)(lb + (kc * 2 + c) * 512);
                    acc0[c] = __builtin_amdgcn_mfma_f32_16x16x32_bf16(a0, b, acc0[c], 0, 0, 0);
                    acc1[c] = __builtin_amdgcn_mfma_f32_16x16x32_bf16(a1, b, acc1[c], 0, 0, 0);
                }
            }
        }
    }

    // epilogue: lrelu, bf16 store, block-local stats
#pragma unroll
    for (int c = 0; c < 2; ++c) {
        float s = 0.f, qq = 0.f;
        const int col = half * 32 + c * 16 + am;
#pragma unroll
        for (int j = 0; j < 4; ++j) {
            {
                float x = acc0[c][j];
                float z = (x > 0.f) ? x : 0.01f * x;
                int row = base + grp * 4 + j;
                if (row < N) zout[(size_t)row * 128 + col] = f2bf(z);
                s += z;
                qq += z * z;
            }
            {
                float x = acc1[c][j];
                float z = (x > 0.f) ? x : 0.01f * x;
                int row = base + 16 + grp * 4 + j;
                if (row < N) zout[(size_t)row * 128 + col] = f2bf(z);
                s += z;
                qq += z * z;
            }
        }
        s += __shfl_xor(s, 16);
        qq += __shfl_xor(qq, 16);
        s += __shfl_xor(s, 32);
        qq += __shfl_xor(qq, 32);
        if (lane < 16) {
            atomicAdd(&sstat[c * 16 + am], s);
            atomicAdd(&sstat[32 + c * 16 + am], qq);
        }
    }
    __syncthreads();
    if (tid < 32) {
        int cg = half * 32 + tid;
        atomicAdd(stats + cg, sstat[tid]);
        atomicAdd(stats + 128 + cg, sstat[32 + tid]);
    }
}

// ---- finalize two BN stat sets -> per-channel scale/shift ----
__global__ void k_fin(const float* __restrict__ stats,
                      const float* __restrict__ g0, const float* __restrict__ b0,
                      const float* __restrict__ g1, const float* __restrict__ b1,
                      float* __restrict__ ss, int N) {
    int tid = threadIdx.x;
    int set = tid >> 7, c = tid & 127;
    const float* st = stats + set * 256;
    float invN = 1.f / (float)N;
    float m = st[c] * invN;
    float var = st[128 + c] * invN - m * m;
    const float* g = set ? g1 : g0;
    const float* b = set ? b1 : b0;
    float sc = g[c] * rsqrtf(var + 1e-5f);
    float sh = b[c] - m * sc;
    float* o = ss + set * 256;
    o[c] = sc;
    o[128 + c] = sh;
}

// ---- y = z*scale + shift (bf16 out, with zero sentinel row N) ----
__global__ void k_aff(const u16* __restrict__ z, const float* __restrict__ ss,
                      u16* __restrict__ y, int N) {
    int v = blockIdx.x * 256 + threadIdx.x;
    int total = (N + 1) * 16;
    if (v >= total) return;
    int row = v >> 4;
    int cb = (v & 15) * 8;
    s16x8 o;
    if (row < N) {
        s16x8 zi = *(const s16x8*)(z + (size_t)row * 128 + cb);
#pragma unroll
        for (int j = 0; j < 8; ++j) {
            float x = bf2f((u16)zi[j]);
            float r = x * ss[cb + j] + ss[128 + cb + j];
            o[j] = (short)f2bf(r);
        }
    } else {
        o = (s16x8){0, 0, 0, 0, 0, 0, 0, 0};
    }
    *(s16x8*)(y + (size_t)row * 128 + cb) = o;
}

// ---- out = bn(z3) + bn(z4), f32 ----
__global__ void k_final(const u16* __restrict__ z3, const u16* __restrict__ z4,
                        const float* __restrict__ ssA, const float* __restrict__ ssB,
                        float* __restrict__ out, int N) {
    int v = blockIdx.x * 256 + threadIdx.x;
    int total = N * 32;
    if (v >= total) return;
    int row = v >> 5;
    int cb = (v & 31) * 4;
    s16x4 a = *(const s16x4*)(z3 + (size_t)row * 128 + cb);
    s16x4 b = *(const s16x4*)(z4 + (size_t)row * 128 + cb);
    f32x4 o;
#pragma unroll
    for (int j = 0; j < 4; ++j) {
        int c = cb + j;
        o[j] = bf2f((u16)a[j]) * ssA[c] + ssA[128 + c] +
               bf2f((u16)b[j]) * ssB[c] + ssB[128 + c];
    }
    *(f32x4*)(out + (size_t)row * 128 + cb) = o;
}

extern "C" void kernel_launch(void* const* d_in, const int* in_sizes, int n_in,
                              void* d_out, int out_size, void* d_ws, size_t ws_size,
                              hipStream_t stream) {
    const float* feat = (const float*)d_in[0];
    const int* nbr31 = (const int*)d_in[1];
    const int* nbr13 = (const int*)d_in[2];
    const float* W1 = (const float*)d_in[3];
    const float* W12 = (const float*)d_in[4];
    const float* W2 = (const float*)d_in[5];
    const float* W3 = (const float*)d_in[6];
    const float* g0 = (const float*)d_in[7];
    const float* b0 = (const float*)d_in[8];
    const float* g02 = (const float*)d_in[9];
    const float* b02 = (const float*)d_in[10];
    const float* g1 = (const float*)d_in[11];
    const float* b1 = (const float*)d_in[12];
    const float* g2 = (const float*)d_in[13];
    const float* b2 = (const float*)d_in[14];
    float* out = (float*)d_out;
    const int N = in_sizes[0] / 64;  // 200000

    char* p = (char*)d_ws;
    auto alloc = [&](size_t bytes) {
        char* r = p;
        p += (bytes + 255) & ~(size_t)255;
        return r;
    };
    float* stats = (float*)alloc(4 * 256 * sizeof(float));
    float* ss = (float*)alloc(4 * 256 * sizeof(float));
    u16* featbf = (u16*)alloc((size_t)(N + 1) * 64 * 2);
    u16* w1 = (u16*)alloc((size_t)9 * 64 * 128 * 2);
    u16* w2 = (u16*)alloc((size_t)9 * 64 * 128 * 2);
    u16* w12 = (u16*)alloc((size_t)9 * 128 * 128 * 2);
    u16* w3 = (u16*)alloc((size_t)9 * 128 * 128 * 2);
    u16* zA = (u16*)alloc((size_t)N * 128 * 2);
    u16* zB = (u16*)alloc((size_t)N * 128 * 2);
    u16* y1 = (u16*)alloc((size_t)(N + 1) * 128 * 2);
    u16* y2 = (u16*)alloc((size_t)(N + 1) * 128 * 2);

    hipMemsetAsync(stats, 0, 4 * 256 * sizeof(float), stream);

    int totF = (N + 1) * 64;
    k_feat2bf<<<(totF / 8 + 255) / 256, 256, 0, stream>>>(feat, featbf, totF, N * 64);
    k_swz<<<(9 * 64 * 128 + 255) / 256, 256, 0, stream>>>(W1, w1, 64);
    k_swz<<<(9 * 64 * 128 + 255) / 256, 256, 0, stream>>>(W2, w2, 64);
    k_swz<<<(9 * 128 * 128 + 255) / 256, 256, 0, stream>>>(W12, w12, 128);
    k_swz<<<(9 * 128 * 128 + 255) / 256, 256, 0, stream>>>(W3, w3, 128);

    // flat grid with XCD-grouping remap: 8 * 4 * ceil(npairs/8) blocks
    int nvr = (N + 511) / 512;
    int npairs = 2 * nvr;
    int nblk = 8 * 4 * ((npairs + 7) / 8);

    // stage 1: cz=0: conv(nbr31, W1) -> zA/stats0 ; cz=1: conv(nbr13, W2) -> zB/stats1
    k_conv<64><<<nblk, 1024, 0, stream>>>(
        featbf, featbf, nbr31, nbr13, w1, w2, zA, zB, stats + 0, stats + 256, N);
    k_fin<<<1, 256, 0, stream>>>(stats, g0, b0, g1, b1, ss, N);
    int ablk = ((N + 1) * 16 + 255) / 256;
    k_aff<<<ablk, 256, 0, stream>>>(zA, ss + 0, y1, N);
    k_aff<<<ablk, 256, 0, stream>>>(zB, ss + 256, y2, N);
    // stage 2: cz=0: conv(y1, nbr13, W12) -> zA ; cz=1: conv(y2, nbr31, W3) -> zB
    k_conv<128><<<nblk, 1024, 0, stream>>>(
        y1, y2, nbr13, nbr31, w12, w3, zA, zB, stats + 512, stats + 768, N);
    k_fin<<<1, 256, 0, stream>>>(stats + 512, g02, b02, g2, b2, ss + 512, N);
    k_final<<<(N * 32 + 255) / 256, 256, 0, stream>>>(zA, zB, ss + 512, ss + 768, out, N);
}

// Round 8
// 406.963 us; speedup vs baseline: 1.1844x; 1.1147x over previous
//
#include <hip/hip_runtime.h>
#include <hip/hip_bf16.h>

typedef unsigned short u16;
typedef unsigned int u32;
typedef __attribute__((ext_vector_type(8))) short s16x8;
typedef __attribute__((ext_vector_type(4))) short s16x4;
typedef __attribute__((ext_vector_type(4))) float f32x4;

__device__ inline u16 f2bf(float x) {
    u32 u = __float_as_uint(x);
    u32 r = (u + 0x7fffu + ((u >> 16) & 1u)) >> 16;
    return (u16)r;
}
__device__ inline float bf2f(u16 u) {
    return __uint_as_float(((u32)u) << 16);
}

// ---- features f32 -> bf16, with zero sentinel row at index N ----
__global__ void k_feat2bf(const float* __restrict__ f, u16* __restrict__ o,
                          int total, int nvalid) {
    int i = (blockIdx.x * 256 + threadIdx.x) * 8;
    if (i >= total) return;
    s16x8 v;
#pragma unroll
    for (int j = 0; j < 8; ++j) {
        float x = (i + j < nvalid) ? f[i + j] : 0.f;
        v[j] = (short)f2bf(x);
    }
    *(s16x8*)(o + i) = v;
}

// ---- weight swizzle: W[9][cin][128] f32 -> MFMA-B fragment-packed bf16 ----
__global__ void k_swz(const float* __restrict__ W, u16* __restrict__ o, int cin) {
    int i = blockIdx.x * 256 + threadIdx.x;
    int total = 9 * cin * 128;
    if (i >= total) return;
    int j = i & 7;
    int l = (i >> 3) & 63;
    int fr = i >> 9;
    int ct = fr & 7;
    int rest = fr >> 3;
    int kcn = cin >> 5;
    int kc = rest % kcn;
    int t = rest / kcn;
    int kk = kc * 32 + (l >> 4) * 8 + j;
    int c = ct * 16 + (l & 15);
    o[i] = f2bf(W[(t * cin + kk) * 128 + c]);
}

// ---- gather-conv: 1024 thr (16 waves x 32 voxels) x 32 output cols.
// Flat 1-D grid with XCD-grouping remap (4 column-quarter blocks of one
// (voxel-range, conv) group co-resident on one XCD -> shared L2 for gathers).
// Pair-level tap skipping; per tap: batch-load all A frags, then MFMA from
// LDS-staged weights. launch_bounds(1024,4): 128 VGPR budget, no spill.
template <int CIN>
__global__ __launch_bounds__(1024, 4) void k_conv(
    const u16* __restrict__ srcA, const u16* __restrict__ srcB,
    const int* __restrict__ nbrA, const int* __restrict__ nbrB,
    const u16* __restrict__ wA, const u16* __restrict__ wB,
    u16* __restrict__ zoutA, u16* __restrict__ zoutB,
    float* __restrict__ statsA, float* __restrict__ statsB,
    int N) {
    constexpr int KC = CIN / 32;
    constexpr int FR = 9 * KC * 2;    // frags staged (2 col-tiles of 16)
    __shared__ u16 wl[FR * 512];
    __shared__ float sstat[64];

    // ---- block-id remap: i = c + 8*(4q + h); group p = 8q + c; quarter h ----
    const int nvr = (N + 511) >> 9;
    const int npairs = 2 * nvr;
    const int i = blockIdx.x;
    const int c8 = i & 7;
    const int m = i >> 3;
    const int h = m & 3;
    const int q = m >> 2;
    const int p = 8 * q + c8;
    if (p >= npairs) return;
    const int vr = p % nvr;
    const int cz = p / nvr;
    const int half = h;

    const u16* __restrict__ src = cz ? srcB : srcA;
    const int* __restrict__ nbr = cz ? nbrB : nbrA;
    const u16* __restrict__ w = cz ? wB : wA;
    u16* __restrict__ zout = cz ? zoutB : zoutA;
    float* __restrict__ stats = cz ? statsB : statsA;

    const int tid = threadIdx.x;

    // stage this quarter's weights for all taps; zero stats
    for (int ii = tid; ii < FR * 64; ii += 1024) {
        int pp = ii & 63;
        int f = ii >> 6;          // (t*KC+kc)*2 + ctp
        int ctp = f & 1;
        int tk = f >> 1;
        s16x8 v = *(const s16x8*)(w + ((size_t)(tk * 8 + half * 2 + ctp)) * 512 + pp * 8);
        *(s16x8*)&wl[(size_t)f * 512 + pp * 8] = v;
    }
    if (tid < 64) sstat[tid] = 0.f;
    __syncthreads();

    const int lane = tid & 63;
    const int wv = tid >> 6;
    const int base = vr * 512 + wv * 32;
    const int am = lane & 15;
    const int grp = lane >> 4;
    const int vi0 = base + am;
    const int vi1 = base + 16 + am;

    int r0[9], r1[9];
#pragma unroll
    for (int t = 0; t < 9; ++t) {
        r0[t] = (vi0 < N) ? nbr[t * N + vi0] : N;
        r1[t] = (vi1 < N) ? nbr[t * N + vi1] : N;
    }

    f32x4 acc0[2], acc1[2];
#pragma unroll
    for (int c = 0; c < 2; ++c) {
        acc0[c] = (f32x4){0.f, 0.f, 0.f, 0.f};
        acc1[c] = (f32x4){0.f, 0.f, 0.f, 0.f};
    }

#pragma unroll
    for (int t = 0; t < 9; ++t) {
        if (__any((r0[t] != N) || (r1[t] != N))) {
            const u16* sp0 = src + (size_t)r0[t] * CIN + grp * 8;
            const u16* sp1 = src + (size_t)r1[t] * CIN + grp * 8;
            // batch all A loads for this tap (pay gather latency once)
            s16x8 a0[KC], a1[KC];
#pragma unroll
            for (int kc = 0; kc < KC; ++kc) {
                a0[kc] = *(const s16x8*)(sp0 + kc * 32);
                a1[kc] = *(const s16x8*)(sp1 + kc * 32);
            }
            const u16* lb = wl + (size_t)t * (KC * 2) * 512 + lane * 8;
#pragma unroll
            for (int kc = 0; kc < KC; ++kc) {
#pragma unroll
                for (int c = 0; c < 2; ++c) {
                    s16x8 b = *(const s16x8*)(lb + (kc * 2 + c) * 512);
                    acc0[c] = __builtin_amdgcn_mfma_f32_16x16x32_bf16(a0[kc], b, acc0[c], 0, 0, 0);
                    acc1[c] = __builtin_amdgcn_mfma_f32_16x16x32_bf16(a1[kc], b, acc1[c], 0, 0, 0);
                }
            }
        }
    }

    // epilogue: lrelu, bf16 store, block-local stats
#pragma unroll
    for (int c = 0; c < 2; ++c) {
        float s = 0.f, qq = 0.f;
        const int col = half * 32 + c * 16 + am;
#pragma unroll
        for (int j = 0; j < 4; ++j) {
            {
                float x = acc0[c][j];
                float z = (x > 0.f) ? x : 0.01f * x;
                int row = base + grp * 4 + j;
                if (row < N) zout[(size_t)row * 128 + col] = f2bf(z);
                s += z;
                qq += z * z;
            }
            {
                float x = acc1[c][j];
                float z = (x > 0.f) ? x : 0.01f * x;
                int row = base + 16 + grp * 4 + j;
                if (row < N) zout[(size_t)row * 128 + col] = f2bf(z);
                s += z;
                qq += z * z;
            }
        }
        s += __shfl_xor(s, 16);
        qq += __shfl_xor(qq, 16);
        s += __shfl_xor(s, 32);
        qq += __shfl_xor(qq, 32);
        if (lane < 16) {
            atomicAdd(&sstat[c * 16 + am], s);
            atomicAdd(&sstat[32 + c * 16 + am], qq);
        }
    }
    __syncthreads();
    if (tid < 32) {
        int cg = half * 32 + tid;
        atomicAdd(stats + cg, sstat[tid]);
        atomicAdd(stats + 128 + cg, sstat[32 + tid]);
    }
}

// ---- finalize two BN stat sets -> per-channel scale/shift ----
__global__ void k_fin(const float* __restrict__ stats,
                      const float* __restrict__ g0, const float* __restrict__ b0,
                      const float* __restrict__ g1, const float* __restrict__ b1,
                      float* __restrict__ ss, int N) {
    int tid = threadIdx.x;
    int set = tid >> 7, c = tid & 127;
    const float* st = stats + set * 256;
    float invN = 1.f / (float)N;
    float m = st[c] * invN;
    float var = st[128 + c] * invN - m * m;
    const float* g = set ? g1 : g0;
    const float* b = set ? b1 : b0;
    float sc = g[c] * rsqrtf(var + 1e-5f);
    float sh = b[c] - m * sc;
    float* o = ss + set * 256;
    o[c] = sc;
    o[128 + c] = sh;
}

// ---- y = z*scale + shift (bf16 out, with zero sentinel row N) ----
__global__ void k_aff(const u16* __restrict__ z, const float* __restrict__ ss,
                      u16* __restrict__ y, int N) {
    int v = blockIdx.x * 256 + threadIdx.x;
    int total = (N + 1) * 16;
    if (v >= total) return;
    int row = v >> 4;
    int cb = (v & 15) * 8;
    s16x8 o;
    if (row < N) {
        s16x8 zi = *(const s16x8*)(z + (size_t)row * 128 + cb);
#pragma unroll
        for (int j = 0; j < 8; ++j) {
            float x = bf2f((u16)zi[j]);
            float r = x * ss[cb + j] + ss[128 + cb + j];
            o[j] = (short)f2bf(r);
        }
    } else {
        o = (s16x8){0, 0, 0, 0, 0, 0, 0, 0};
    }
    *(s16x8*)(y + (size_t)row * 128 + cb) = o;
}

// ---- out = bn(z3) + bn(z4), f32 ----
__global__ void k_final(const u16* __restrict__ z3, const u16* __restrict__ z4,
                        const float* __restrict__ ssA, const float* __restrict__ ssB,
                        float* __restrict__ out, int N) {
    int v = blockIdx.x * 256 + threadIdx.x;
    int total = N * 32;
    if (v >= total) return;
    int row = v >> 5;
    int cb = (v & 31) * 4;
    s16x4 a = *(const s16x4*)(z3 + (size_t)row * 128 + cb);
    s16x4 b = *(const s16x4*)(z4 + (size_t)row * 128 + cb);
    f32x4 o;
#pragma unroll
    for (int j = 0; j < 4; ++j) {
        int c = cb + j;
        o[j] = bf2f((u16)a[j]) * ssA[c] + ssA[128 + c] +
               bf2f((u16)b[j]) * ssB[c] + ssB[128 + c];
    }
    *(f32x4*)(out + (size_t)row * 128 + cb) = o;
}

extern "C" void kernel_launch(void* const* d_in, const int* in_sizes, int n_in,
                              void* d_out, int out_size, void* d_ws, size_t ws_size,
                              hipStream_t stream) {
    const float* feat = (const float*)d_in[0];
    const int* nbr31 = (const int*)d_in[1];
    const int* nbr13 = (const int*)d_in[2];
    const float* W1 = (const float*)d_in[3];
    const float* W12 = (const float*)d_in[4];
    const float* W2 = (const float*)d_in[5];
    const float* W3 = (const float*)d_in[6];
    const float* g0 = (const float*)d_in[7];
    const float* b0 = (const float*)d_in[8];
    const float* g02 = (const float*)d_in[9];
    const float* b02 = (const float*)d_in[10];
    const float* g1 = (const float*)d_in[11];
    const float* b1 = (const float*)d_in[12];
    const float* g2 = (const float*)d_in[13];
    const float* b2 = (const float*)d_in[14];
    float* out = (float*)d_out;
    const int N = in_sizes[0] / 64;  // 200000

    char* p = (char*)d_ws;
    auto alloc = [&](size_t bytes) {
        char* r = p;
        p += (bytes + 255) & ~(size_t)255;
        return r;
    };
    float* stats = (float*)alloc(4 * 256 * sizeof(float));
    float* ss = (float*)alloc(4 * 256 * sizeof(float));
    u16* featbf = (u16*)alloc((size_t)(N + 1) * 64 * 2);
    u16* w1 = (u16*)alloc((size_t)9 * 64 * 128 * 2);
    u16* w2 = (u16*)alloc((size_t)9 * 64 * 128 * 2);
    u16* w12 = (u16*)alloc((size_t)9 * 128 * 128 * 2);
    u16* w3 = (u16*)alloc((size_t)9 * 128 * 128 * 2);
    u16* zA = (u16*)alloc((size_t)N * 128 * 2);
    u16* zB = (u16*)alloc((size_t)N * 128 * 2);
    u16* y1 = (u16*)alloc((size_t)(N + 1) * 128 * 2);
    u16* y2 = (u16*)alloc((size_t)(N + 1) * 128 * 2);

    hipMemsetAsync(stats, 0, 4 * 256 * sizeof(float), stream);

    int totF = (N + 1) * 64;
    k_feat2bf<<<(totF / 8 + 255) / 256, 256, 0, stream>>>(feat, featbf, totF, N * 64);
    k_swz<<<(9 * 64 * 128 + 255) / 256, 256, 0, stream>>>(W1, w1, 64);
    k_swz<<<(9 * 64 * 128 + 255) / 256, 256, 0, stream>>>(W2, w2, 64);
    k_swz<<<(9 * 128 * 128 + 255) / 256, 256, 0, stream>>>(W12, w12, 128);
    k_swz<<<(9 * 128 * 128 + 255) / 256, 256, 0, stream>>>(W3, w3, 128);

    // flat grid with XCD-grouping remap: 8 * 4 * ceil(npairs/8) blocks
    int nvr = (N + 511) / 512;
    int npairs = 2 * nvr;
    int nblk = 8 * 4 * ((npairs + 7) / 8);

    // stage 1: cz=0: conv(nbr31, W1) -> zA/stats0 ; cz=1: conv(nbr13, W2) -> zB/stats1
    k_conv<64><<<nblk, 1024, 0, stream>>>(
        featbf, featbf, nbr31, nbr13, w1, w2, zA, zB, stats + 0, stats + 256, N);
    k_fin<<<1, 256, 0, stream>>>(stats, g0, b0, g1, b1, ss, N);
    int ablk = ((N + 1) * 16 + 255) / 256;
    k_aff<<<ablk, 256, 0, stream>>>(zA, ss + 0, y1, N);
    k_aff<<<ablk, 256, 0, stream>>>(zB, ss + 256, y2, N);
    // stage 2: cz=0: conv(y1, nbr13, W12) -> zA ; cz=1: conv(y2, nbr31, W3) -> zB
    k_conv<128><<<nblk, 1024, 0, stream>>>(
        y1, y2, nbr13, nbr31, w12, w3, zA, zB, stats + 512, stats + 768, N);
    k_fin<<<1, 256, 0, stream>>>(stats + 512, g02, b02, g2, b2, ss + 512, N);
    k_final<<<(N * 32 + 255) / 256, 256, 0, stream>>>(zA, zB, ss + 512, ss + 768, out, N);
}